// Round 10
// baseline (101.619 us; speedup 1.0000x reference)
//
#include <hip/hip_runtime.h>

// FerroelectricBasisConv2d on MI355X — round 10: table-driven.
// Structural identity: out[b,co,p] = out_bias[co] + sum_{cin,ij} F_{co,cin,ij}(x[b,cin,tap(p,ij)])
// where F(x) = sum_{kk} c*(Ps*tanh(k*(x+Ec*(0.8+0.2*sigmoid(10*(x+Ec))))) + b)
// Only 32*16*9 = 4608 distinct scalar functions. Prep builds piecewise-linear
// tables from EXACT math (193 entries, x in [-6,6], h=1/16, float2 {F, dF}).
// Main: 144 lookups/pixel, ZERO transcendentals (R5->R7 delta showed wave64
// trans costs ~16-21cy -> 3 trans/eval was ~48 of 62 cy: the real bottleneck).
// bid layout puts co in low 5 bits: all 1024 blocks co-resident, each XCD's
// blocks touch 4 cos x 222KB ~= 0.9MB of tables -> L2-resident scatter reads.

#define LOG2E 1.4426950408889634f
#define ENT 193   // entries per table: x_e = -6 + e/16, e in [0,192]

__device__ __forceinline__ float sig_exact(float z) {
    return 1.f / (1.f + __builtin_amdgcn_exp2f(-LOG2E * z));
}
__device__ __forceinline__ float tanh_exact(float z) {
    return 1.f - 2.f / (1.f + __builtin_amdgcn_exp2f(2.f * LOG2E * z));
}

__global__ __launch_bounds__(256) void ferro_prep(
    const float* __restrict__ k, const float* __restrict__ Ec,
    const float* __restrict__ Ps, const float* __restrict__ bias,
    const float* __restrict__ coef, float2* __restrict__ tab)
{
    // block = co*9 + ij; threads 0..192 each own one table entry e
    const int blk = blockIdx.x;
    const int co  = blk / 9;
    const int ij  = blk - co * 9;
    const int e   = threadIdx.x;
    if (e >= ENT) return;
    const float xe = -6.f + (float)e * 0.0625f;

    for (int cin = 0; cin < 16; ++cin) {
        const int pb = (co * 16 + cin) * 27 + ij;   // + kk*9 ; uniform -> s_load
        float F[2];
        #pragma unroll
        for (int q = 0; q < 2; ++q) {
            float xv = xe + (float)q * 0.0625f;
            float acc = 0.f;
            #pragma unroll
            for (int kk = 0; kk < 3; ++kk) {
                const int pi = pb + kk * 9;
                float kv = k[pi], ev = Ec[pi], pv = Ps[pi], bv = bias[pi], cv = coef[pi];
                float s   = sig_exact(10.f * (xv + ev));
                float mom = fmaf(0.2f, s, 0.8f);
                float sh  = fmaf(ev, mom, xv);
                acc += cv * fmaf(pv, tanh_exact(kv * sh), bv);
            }
            F[q] = acc;
        }
        tab[((co * 16 + cin) * 9 + ij) * ENT + e] = make_float2(F[0], F[1] - F[0]);
    }
}

__global__ __launch_bounds__(256, 4) void ferro_main(
    const float* __restrict__ x, const float2* __restrict__ tab,
    const float* __restrict__ out_bias, float* __restrict__ out)
{
    // bid = b*256 + rq*32 + co  (co in LOW bits -> per-XCD table locality)
    const int bid = blockIdx.x;
    const int co  = bid & 31;
    const int rq  = (bid >> 5) & 7;   // row-quad: rows 4rq..4rq+3
    const int b   = bid >> 8;
    const int tid = threadIdx.x;

    __shared__ float xs[16 * 6 * 34];  // [cin16][row6][col34], rows r0-1..r0+4
    __shared__ float red[256];

    // ---- stage x strip (zero-padded) ----
    const int r0 = rq * 4;
    const float* xb = x + b * 16384;
    for (int idx = tid; idx < 16 * 204; idx += 256) {
        int cin  = idx / 204;
        int rem  = idx - cin * 204;
        int row  = rem / 34;
        int colp = rem - row * 34;
        int gr = r0 + row - 1;
        int gc = colp - 1;
        float v = 0.f;
        if ((unsigned)gr < 32u && (unsigned)gc < 32u)
            v = xb[(cin * 32 + gr) * 32 + gc];
        xs[idx] = v;
    }
    __syncthreads();

    // ---- lookup loop: 2 threads per pixel (cin halves), 72 lookups each ----
    const int ch  = tid >> 7;          // cin half
    const int pix = tid & 127;
    const int lr  = pix >> 5;          // 0..3
    const int col = pix & 31;

    const float2* tb = tab + (size_t)(co * 16 + ch * 8) * 9 * ENT;
    float acc = 0.f;

    #pragma unroll 1
    for (int c = 0; c < 8; ++c) {
        const float*  xr = &xs[(ch * 8 + c) * 204 + lr * 34 + col];
        const float2* tc = tb + c * 9 * ENT;
        #pragma unroll
        for (int ij = 0; ij < 9; ++ij) {
            const int i = ij / 3, j = ij - (ij / 3) * 3;
            float xv = xr[i * 34 + j];
            float t  = fmaf(xv, 16.f, 96.f);          // (x+6)*16
            t = fminf(fmaxf(t, 0.f), 192.f);          // v_med3 clamp
            int   i0 = (int)t;
            float fr = t - (float)i0;
            float2 p = tc[ij * ENT + i0];             // 8B L2 scatter read
            acc += fmaf(fr, p.y, p.x);
        }
    }

    red[tid] = acc;
    __syncthreads();

    // ---- combine cin halves, add out_bias, store once per pixel ----
    if (tid < 128) {
        int lr2  = tid >> 5;
        int col2 = tid & 31;
        float v = red[tid] + red[tid + 128] + out_bias[co];
        out[((b * 32 + co) * 32 + (r0 + lr2)) * 32 + col2] = v;
    }
}

extern "C" void kernel_launch(void* const* d_in, const int* in_sizes, int n_in,
                              void* d_out, int out_size, void* d_ws, size_t ws_size,
                              hipStream_t stream) {
    const float* x        = (const float*)d_in[0];
    const float* k        = (const float*)d_in[1];
    const float* Ec       = (const float*)d_in[2];
    const float* Ps       = (const float*)d_in[3];
    const float* bias     = (const float*)d_in[4];
    const float* coef     = (const float*)d_in[5];
    const float* out_bias = (const float*)d_in[6];
    float* out = (float*)d_out;

    float2* tab = (float2*)d_ws;   // 4608 tables * 193 entries * 8B = 7.11 MB

    ferro_prep<<<dim3(32 * 9), dim3(256), 0, stream>>>(k, Ec, Ps, bias, coef, tab);
    ferro_main<<<dim3(1024), dim3(256), 0, stream>>>(x, tab, out_bias, out);
}